// Round 9
// baseline (1592.506 us; speedup 1.0000x reference)
//
#include <hip/hip_runtime.h>
#include <cstdint>
#include <cstddef>

// Problem constants (fixed by setup_inputs)
constexpr int B_  = 16;
constexpr int T_  = 1024;
constexpr int C_  = 768;
constexpr int H_  = 12;
constexpr int HD_ = 64;
constexpr int BT_ = B_ * T_;      // 16384
constexpr int C3_ = 3 * C_;       // 2304
constexpr int QK2_ = 2 * C_;      // 1536 (packed q|k row stride)
constexpr int FF_ = 4 * C_;       // 3072
constexpr int MCH_ = 8192;        // MoE row chunk

typedef __bf16 bf16x8 __attribute__((ext_vector_type(8)));
typedef float  floatx4 __attribute__((ext_vector_type(4)));
typedef unsigned short u16x8 __attribute__((ext_vector_type(8)));

__device__ inline float bf2f(unsigned short u) {
  union { unsigned int i; float f; } x; x.i = ((unsigned int)u) << 16; return x.f;
}
__device__ inline unsigned short f2bf(float f) {
  union { float f; unsigned int i; } x; x.f = f;
  unsigned int u = x.i;
  u += 0x7fffu + ((u >> 16) & 1u);   // round-to-nearest-even
  return (unsigned short)(u >> 16);
}

// async global->LDS, 16B per lane, LDS dest = wave-uniform base + lane*16
#define GLOAD_LDS16(gp, lp)                                              \
  __builtin_amdgcn_global_load_lds(                                      \
      (__attribute__((address_space(1))) void*)(gp),                     \
      (__attribute__((address_space(3))) void*)(lp), 16, 0, 0)

// ---------------------------------------------------------------------------
// LayerNorm: one block (256 threads) per row of 768. f32 in, bf16 out.
// GATE: fused MoE gating (h2 @ wg -> softmax -> gates), saves a kernel +
// a full h2 re-read; uses f32 pre-quantization values (closer to reference).
// ---------------------------------------------------------------------------
template <bool GATE>
__launch_bounds__(256)
__global__ void ln_kernel(const float* __restrict__ x, const float* __restrict__ w,
                          const float* __restrict__ b, unsigned short* __restrict__ out,
                          const float* __restrict__ wg, float* __restrict__ gates) {
  int row = blockIdx.x;
  int tid = threadIdx.x;
  const float* xr = x + (size_t)row * C_;
  float v0 = xr[tid], v1 = xr[tid + 256], v2 = xr[tid + 512];
  float s  = v0 + v1 + v2;
  float ss = v0 * v0 + v1 * v1 + v2 * v2;
#pragma unroll
  for (int off = 32; off > 0; off >>= 1) {
    s  += __shfl_down(s, off, 64);
    ss += __shfl_down(ss, off, 64);
  }
  __shared__ float red[8];
  int wid = tid >> 6;
  if ((tid & 63) == 0) { red[wid] = s; red[4 + wid] = ss; }
  __syncthreads();
  float st  = red[0] + red[1] + red[2] + red[3];
  float sst = red[4] + red[5] + red[6] + red[7];
  float mean = st * (1.0f / C_);
  float var  = sst * (1.0f / C_) - mean * mean;
  float rstd = rsqrtf(var + 1e-5f);
  float h0 = (v0 - mean) * rstd * w[tid]       + b[tid];
  float h1 = (v1 - mean) * rstd * w[tid + 256] + b[tid + 256];
  float h2 = (v2 - mean) * rstd * w[tid + 512] + b[tid + 512];
  unsigned short* orow = out + (size_t)row * C_;
  orow[tid]       = f2bf(h0);
  orow[tid + 256] = f2bf(h1);
  orow[tid + 512] = f2bf(h2);

  if (GATE) {
    float a0 = h0 * wg[2 * tid]     + h1 * wg[2 * (tid + 256)]     + h2 * wg[2 * (tid + 512)];
    float a1 = h0 * wg[2 * tid + 1] + h1 * wg[2 * (tid + 256) + 1] + h2 * wg[2 * (tid + 512) + 1];
#pragma unroll
    for (int off = 32; off > 0; off >>= 1) {
      a0 += __shfl_down(a0, off, 64);
      a1 += __shfl_down(a1, off, 64);
    }
    __shared__ float redg[8];
    if ((tid & 63) == 0) { redg[wid] = a0; redg[4 + wid] = a1; }
    __syncthreads();
    if (tid == 0) {
      float A0 = redg[0] + redg[1] + redg[2] + redg[3];
      float A1 = redg[4] + redg[5] + redg[6] + redg[7];
      float m  = fmaxf(A0, A1);
      float e0 = __expf(A0 - m), e1 = __expf(A1 - m);
      float invs = 1.0f / (e0 + e1);
      const float gnorm = 1.0f / (1.0f + 1e-9f);
      gates[2 * row]     = e0 * invs * gnorm;
      gates[2 * row + 1] = e1 * invs * gnorm;
    }
  }
}

// ---------------------------------------------------------------------------
// Batched transpose+convert: all weight matrices in ONE launch.
// ---------------------------------------------------------------------------
struct CtJobs {
  const float* in[8];
  unsigned short* out[8];
  int K[8], N[8], tX[8];
  int t0[9];
};

__launch_bounds__(256)
__global__ void convT_batch(CtJobs J) {
  __shared__ float t[32][33];
  int bid = blockIdx.x;
  int ji = 0;
#pragma unroll
  for (int i = 0; i < 7; ++i) ji += (bid >= J.t0[i + 1]) ? 1 : 0;
  const float* in = J.in[ji];
  unsigned short* out = J.out[ji];
  const int K = J.K[ji], N = J.N[ji];
  const int lt = bid - J.t0[ji];
  const int bx = lt % J.tX[ji], by = lt / J.tX[ji];
  const int n0 = bx * 32, k0 = by * 32;
  const int tx = threadIdx.x & 31, ty = threadIdx.x >> 5;  // 8 rows per pass
#pragma unroll
  for (int r = 0; r < 32; r += 8)
    t[r + ty][tx] = in[(size_t)(k0 + r + ty) * N + n0 + tx];
  __syncthreads();
#pragma unroll
  for (int r = 0; r < 32; r += 8)
    out[(size_t)(n0 + r + ty) * K + k0 + tx] = f2bf(t[tx][r + ty]);
}

// ---------------------------------------------------------------------------
// bf16 MFMA GEMM: C = post(A @ Bt^T). 128x128 tile / 256 threads, T1 swizzle.
// VSPLIT (qkv only): cols [0,2C) -> packed qk; cols [2C,3C) -> vT (V^T).
// ZB: blockIdx.z selects expert; COMBINE then uses atomicAdd.
// ---------------------------------------------------------------------------
template <int ACT, bool BIAS, bool RES, bool COMBINE, bool OUTBF16,
          bool VSPLIT = false, bool ZB = false>
__launch_bounds__(256)
__global__ void gemm_bf16(const unsigned short* __restrict__ A,
                          const unsigned short* __restrict__ Bt,
                          const float* __restrict__ bias,
                          const float* __restrict__ Rres,
                          const float* __restrict__ gates2, int eidx,
                          void* __restrict__ Cout,
                          unsigned short* __restrict__ vtout,
                          int M, int N, int K,
                          size_t zsA, size_t zsB) {
  __shared__ __attribute__((aligned(16))) unsigned short Als[8192];
  __shared__ __attribute__((aligned(16))) unsigned short Bls[8192];
  const int tid  = threadIdx.x;
  const int wave = tid >> 6, lane = tid & 63;
  const int wr = wave >> 1, wc = wave & 1;

  if (ZB) {
    A  += (size_t)blockIdx.z * zsA;
    Bt += (size_t)blockIdx.z * zsB;
    eidx = (int)blockIdx.z;
  }

  // XCD-aware bijective swizzle (all grids here have nwg % 8 == 0)
  int bx = blockIdx.x, by = blockIdx.y;
  {
    const int nbx = gridDim.x;
    const int nwg = nbx * gridDim.y;
    if ((nwg & 7) == 0) {
      const int bid = by * nbx + bx;
      const int swz = (bid & 7) * (nwg >> 3) + (bid >> 3);
      by = swz / nbx; bx = swz - by * nbx;
    }
  }
  const int m0 = by * 128, n0 = bx * 128;

  const int srow = wave * 32 + (lane >> 3);
  const int skg  = (lane & 7) ^ ((lane >> 3) & 7);   // swizzled k-granule
  const unsigned short* Ap = A  + (size_t)(m0 + srow) * K + skg * 8;
  const unsigned short* Bp = Bt + (size_t)(n0 + srow) * K + skg * 8;
  unsigned short* AlsW = Als + wave * 2048;
  unsigned short* BlsW = Bls + wave * 2048;

  floatx4 acc[4][4];
#pragma unroll
  for (int i = 0; i < 4; ++i)
#pragma unroll
    for (int j = 0; j < 4; ++j) acc[i][j] = floatx4{0.f, 0.f, 0.f, 0.f};

  const int q  = lane >> 4;
  const int ml = lane & 15;
  const int rsw = ml & 7;

  for (int k0 = 0; k0 < K; k0 += 64) {
    __syncthreads();
#pragma unroll
    for (int i = 0; i < 4; ++i) {
      GLOAD_LDS16(Ap + (size_t)(i * 8) * K + k0, AlsW + i * 512);
      GLOAD_LDS16(Bp + (size_t)(i * 8) * K + k0, BlsW + i * 512);
    }
    __syncthreads();
#pragma unroll
    for (int ks = 0; ks < 2; ++ks) {
      const int p = (ks * 4 + q) ^ rsw;
      bf16x8 af[4], bfg[4];
#pragma unroll
      for (int i = 0; i < 4; ++i) {
        int ar = wr * 64 + i * 16 + ml;
        af[i]  = *(const bf16x8*)&Als[(ar * 8 + p) * 8];
        int br = wc * 64 + i * 16 + ml;
        bfg[i] = *(const bf16x8*)&Bls[(br * 8 + p) * 8];
      }
#pragma unroll
      for (int i = 0; i < 4; ++i)
#pragma unroll
        for (int j = 0; j < 4; ++j)
          acc[i][j] = __builtin_amdgcn_mfma_f32_16x16x32_bf16(af[i], bfg[j], acc[i][j], 0, 0, 0);
    }
  }

  const int rbase = q * 4;
#pragma unroll
  for (int i = 0; i < 4; ++i) {
    int row = m0 + wr * 64 + i * 16 + rbase;
#pragma unroll
    for (int j = 0; j < 4; ++j) {
      int col = n0 + wc * 64 + j * 16 + ml;
      float bcol = BIAS ? bias[col] : 0.f;
#pragma unroll
      for (int r = 0; r < 4; ++r) {
        float v = acc[i][j][r];
        if (BIAS) v += bcol;
        if (ACT == 1) v = (v >= 0.f) ? v : 0.01f * v;
        if (RES) v += Rres[(size_t)(row + r) * N + col];
        if (COMBINE) {
          float g = gates2[2 * (row + r) + eidx];
          float* op = (float*)Cout + (size_t)(row + r) * N + col;
          if (ZB) atomicAdd(op, g * v);
          else    *op += g * v;
        } else if (VSPLIT) {
          if (col < QK2_) {
            ((unsigned short*)Cout)[(size_t)(row + r) * QK2_ + col] = f2bf(v);
          } else {
            vtout[(size_t)(col - QK2_) * BT_ + row + r] = f2bf(v);
          }
        } else if (OUTBF16) {
          ((unsigned short*)Cout)[(size_t)(row + r) * N + col] = f2bf(v);
        } else {
          ((float*)Cout)[(size_t)(row + r) * N + col] = v;
        }
      }
    }
  }
}

// ---------------------------------------------------------------------------
// 256x256-tile bf16 GEMM -- round-5 proven 4-phase schedule (983 TF in-loop)
// + T1 XCD-aware bijective block swizzle (round-8 counters: FETCH 473 MB vs
// ideal 138 MB -> per-XCD L2 gets the whole working set under default
// round-robin; chunked remap gives each XCD 8 A-panels + B = ~31 MB/XCD).
// 512 threads = 8 waves (2M x 4N), LDS 128 KB, 1 block/CU (VGPR-bound at
// 2 waves/SIMD -- round-7 showed forcing 4 waves/SIMD spills acc to scratch).
// blockIdx.z = expert (z-strides on A/B/C).
// ---------------------------------------------------------------------------
#define GB256_BAR()   asm volatile("s_barrier" ::: "memory")
#define GB256_LGKM0() asm volatile("s_waitcnt lgkmcnt(0)" ::: "memory")

template <int ACT, bool BIAS>
__launch_bounds__(512, 2)
__global__ void gemm256(const unsigned short* __restrict__ A,
                        const unsigned short* __restrict__ Bt,
                        const float* __restrict__ bias,
                        unsigned short* __restrict__ Cout,
                        int M, int N, int K,
                        size_t zsA, size_t zsB, size_t zsC) {
  // [buf(2)][mat(2)][ks(2)][256*32] ushorts = 128 KB
  __shared__ __attribute__((aligned(16))) unsigned short L[65536];
  const int tid = threadIdx.x;
  const int w = tid >> 6, l = tid & 63;
  const int wr = w >> 2, wc = w & 3;
  const int ml = l & 15, q = l >> 4;

  A    += (size_t)blockIdx.z * zsA;
  Bt   += (size_t)blockIdx.z * zsB;
  Cout += (size_t)blockIdx.z * zsC;

  // T1 XCD-aware bijective swizzle on (x,y) within each z-slice
  int bx = blockIdx.x, by = blockIdx.y;
  {
    const int nbx = gridDim.x;
    const int nwg = nbx * gridDim.y;
    if ((nwg & 7) == 0) {
      const int bid = by * nbx + bx;
      const int swz = (bid & 7) * (nwg >> 3) + (bid >> 3);
      by = swz / nbx; bx = swz - by * nbx;
    }
  }
  const int m0 = by * 256, n0 = bx * 256;

  const int srow = l >> 2;                                // row within 16-chunk
  const int sg   = ((l & 3) ^ ((l >> 3) & 3)) * 8;        // swizzled src col (elems)
  const unsigned short* Ast = A  + (size_t)(m0 + srow) * K + sg;
  const unsigned short* Bst = Bt + (size_t)(n0 + srow) * K + sg;
  const int ldsw = w * 1024;                              // wave rows w*32..

#define STG(cb, mat, ks, srcp, kk)                                           \
  do {                                                                       \
    const unsigned short* _s = (srcp) + (size_t)(w * 32) * K + (kk) + (ks) * 32; \
    unsigned short* _d = L + (cb) * 32768 + (mat) * 16384 + (ks) * 8192 + ldsw;  \
    GLOAD_LDS16(_s, _d);                                                     \
    GLOAD_LDS16(_s + (size_t)16 * K, _d + 512);                              \
  } while (0)

  const int dphys = (q ^ ((ml >> 1) & 3)) * 8;
  const int aoff = (wr * 128 + ml) * 32 + dphys;          // + m*512
  const int boff = (wc * 64 + ml) * 32 + dphys;           // + n*512

  floatx4 acc[8][4];
#pragma unroll
  for (int m = 0; m < 8; ++m)
#pragma unroll
    for (int n = 0; n < 4; ++n) acc[m][n] = floatx4{0.f, 0.f, 0.f, 0.f};

  const int NT = K >> 6;

  STG(0, 0, 0, Ast, 0);  STG(0, 1, 0, Bst, 0);
  STG(0, 0, 1, Ast, 0);  STG(0, 1, 1, Bst, 0);
  STG(1, 0, 0, Ast, 64); STG(1, 1, 0, Bst, 64);
  asm volatile("s_waitcnt vmcnt(0)" ::: "memory");
  GB256_BAR();

  for (int j = 0; j < NT; ++j) {
    const int c = j & 1, nx = c ^ 1;
    const int kk1 = (j + 1) << 6, kk2 = (j + 2) << 6;
    const bool st1 = (j + 1 < NT), st2 = (j + 2 < NT);
    bf16x8 bA[4], bB[4];

#define LOAD_A(KS, MH)                                                       \
  _Pragma("unroll")                                                          \
  for (int mq = 0; mq < 4; ++mq)                                             \
    bA[mq] = *(const bf16x8*)&L[c * 32768 + (KS) * 8192 + aoff + ((MH) * 4 + mq) * 512];
#define LOAD_B(KS)                                                           \
  _Pragma("unroll")                                                          \
  for (int n = 0; n < 4; ++n)                                                \
    bB[n] = *(const bf16x8*)&L[c * 32768 + 16384 + (KS) * 8192 + boff + n * 512];
#define MFMA16(MH)                                                           \
  __builtin_amdgcn_s_setprio(1);                                             \
  _Pragma("unroll")                                                          \
  for (int mq = 0; mq < 4; ++mq)                                             \
    _Pragma("unroll")                                                        \
    for (int n = 0; n < 4; ++n)                                              \
      acc[(MH) * 4 + mq][n] = __builtin_amdgcn_mfma_f32_16x16x32_bf16(       \
          bA[mq], bB[n], acc[(MH) * 4 + mq][n], 0, 0, 0);                    \
  __builtin_amdgcn_s_setprio(0);

    // ---- p1: ks0, mh0 ----
    LOAD_B(0); LOAD_A(0, 0);
    if (st1) STG(nx, 0, 1, Ast, kk1);
    GB256_BAR(); GB256_LGKM0();
    MFMA16(0);
    GB256_BAR();

    // ---- p2: ks0, mh1 ----
    LOAD_A(0, 1);
    if (st1) STG(nx, 1, 1, Bst, kk1);
    GB256_BAR(); GB256_LGKM0();
    MFMA16(1);
    GB256_BAR();

    // ---- p3: ks1, mh0 ----
    LOAD_B(1); LOAD_A(1, 0);
    if (st2) STG(c, 0, 0, Ast, kk2);
    GB256_BAR(); GB256_LGKM0();
    MFMA16(0);
    GB256_BAR();

    // ---- p4: ks1, mh1 ----
    LOAD_A(1, 1);
    if (st2) STG(c, 1, 0, Bst, kk2);
    GB256_BAR(); GB256_LGKM0();
    MFMA16(1);
    if (st2)      asm volatile("s_waitcnt vmcnt(4)" ::: "memory");
    else if (st1) asm volatile("s_waitcnt vmcnt(0)" ::: "memory");
    GB256_BAR();
#undef LOAD_A
#undef LOAD_B
#undef MFMA16
  }

#pragma unroll
  for (int m = 0; m < 8; ++m) {
    const int row = m0 + wr * 128 + m * 16 + q * 4;
#pragma unroll
    for (int n = 0; n < 4; ++n) {
      const int col = n0 + wc * 64 + n * 16 + ml;
      const float bcol = BIAS ? bias[col] : 0.f;
#pragma unroll
      for (int r = 0; r < 4; ++r) {
        float v = acc[m][n][r];
        if (BIAS) v += bcol;
        if (ACT == 1) v = (v >= 0.f) ? v : 0.01f * v;
        Cout[(size_t)(row + r) * N + col] = f2bf(v);
      }
    }
  }
#undef STG
}

// ---------------------------------------------------------------------------
// MFMA flash attention, QBLK=128 (8 waves / 512 threads), double-buffered
// K/V staged ONCE per 128 Q-rows; LDS 66.5 KB -> 2 blocks/CU. Per-wave
// dead-tile skip (wave-uniform). qk: [B*T,2C] bf16. vT: [C,B*T]. y: bf16.
// ---------------------------------------------------------------------------
__launch_bounds__(512)
__global__ void attn_kernel(const unsigned short* __restrict__ qk,
                            const unsigned short* __restrict__ vT,
                            unsigned short* __restrict__ y) {
  __shared__ __attribute__((aligned(16))) unsigned short Qls[128 * 64];
  __shared__ __attribute__((aligned(16))) unsigned short K2[2][64 * 64];
  __shared__ __attribute__((aligned(16))) unsigned short V2[2][64 * 64];
  __shared__ __attribute__((aligned(16))) unsigned short Pls[8 * 16 * 72];

  const int tid  = threadIdx.x;
  const int wave = tid >> 6, lane = tid & 63;
  const int quad = lane >> 4, n = lane & 15;
  const int q0 = blockIdx.x * 128;
  const int bh = blockIdx.y;
  const int b = bh / H_, h = bh % H_;
  const size_t qbase = (size_t)b * T_ * QK2_ + (size_t)h * HD_;
  const size_t vbase = (size_t)h * HD_ * BT_ + (size_t)b * T_;

  const int r8 = lane >> 3;            // 0..7
  const int g  = (lane & 7) ^ r8;      // swizzled granule (16B units), row&7 XOR

  // Q stage (once): wave stages its own 16 rows (2 x 8-row GLOADs)
#pragma unroll
  for (int i = 0; i < 2; ++i) {
    int row = wave * 16 + i * 8 + r8;
    GLOAD_LDS16(qk + qbase + (size_t)(q0 + row) * QK2_ + g * 8,
                Qls + wave * 1024 + i * 512);
  }

  // K/V stage: 8 waves x 8 rows each (1 GLOAD K + 1 GLOAD V per wave)
#define STAGE_KV(bf, k0)                                                      \
  do {                                                                        \
    int row = wave * 8 + r8;                                                  \
    GLOAD_LDS16(qk + qbase + (size_t)((k0) + row) * QK2_ + C_ + g * 8,        \
                K2[bf] + wave * 512);                                         \
    GLOAD_LDS16(vT + vbase + (size_t)row * BT_ + (k0) + g * 8,                \
                V2[bf] + wave * 512);                                         \
  } while (0)

  STAGE_KV(0, 0);

  floatx4 O[4];
#pragma unroll
  for (int ct = 0; ct < 4; ++ct) O[ct] = floatx4{0.f, 0.f, 0.f, 0.f};
  float mrow[4] = {-1e30f, -1e30f, -1e30f, -1e30f};
  float lrow[4] = {0.f, 0.f, 0.f, 0.f};

  const int nkt = 2 * blockIdx.x + 2;
  const int dt  = 2 * blockIdx.x + (wave >> 2);   // wave's diagonal tile
  unsigned short* Pw = Pls + wave * (16 * 72);

  for (int kt = 0; kt < nkt; ++kt) {
    const int cur = kt & 1;
    __syncthreads();                    // drains vmcnt(0): buf[cur] ready
    if (kt + 1 < nkt) STAGE_KV(cur ^ 1, (kt + 1) << 6);
    if (kt > dt) continue;              // fully-masked tile for this wave

    floatx4 sacc[4];
#pragma unroll
    for (int ct = 0; ct < 4; ++ct) sacc[ct] = floatx4{0.f, 0.f, 0.f, 0.f};
#pragma unroll
    for (int ks = 0; ks < 2; ++ks) {
      const int ga = (ks * 4 + quad) ^ (n & 7);
      bf16x8 aq = *(const bf16x8*)&Qls[((wave * 16 + n) * 8 + ga) * 8];
#pragma unroll
      for (int ct = 0; ct < 4; ++ct) {
        bf16x8 kb = *(const bf16x8*)&K2[cur][((ct * 16 + n) * 8 + ga) * 8];
        sacc[ct] = __builtin_amdgcn_mfma_f32_16x16x32_bf16(aq, kb, sacc[ct], 0, 0, 0);
      }
    }

    float p[4][4];
#pragma unroll
    for (int ct = 0; ct < 4; ++ct)
#pragma unroll
      for (int r = 0; r < 4; ++r) p[ct][r] = sacc[ct][r] * 0.125f;
    if (kt == dt) {                     // diagonal tile: causal mask
      const int kgb = (kt << 6) + n, qgb = q0 + wave * 16 + quad * 4;
#pragma unroll
      for (int ct = 0; ct < 4; ++ct)
#pragma unroll
        for (int r = 0; r < 4; ++r)
          if (kgb + ct * 16 > qgb + r) p[ct][r] = -1e30f;
    }
#pragma unroll
    for (int r = 0; r < 4; ++r) {
      float tm = fmaxf(fmaxf(p[0][r], p[1][r]), fmaxf(p[2][r], p[3][r]));
      tm = fmaxf(tm, __shfl_xor(tm, 1, 64));
      tm = fmaxf(tm, __shfl_xor(tm, 2, 64));
      tm = fmaxf(tm, __shfl_xor(tm, 4, 64));
      tm = fmaxf(tm, __shfl_xor(tm, 8, 64));
      float mn = fmaxf(mrow[r], tm);
      float alpha = __expf(mrow[r] - mn);
      mrow[r] = mn;
      float ps = 0.f;
#pragma unroll
      for (int ct = 0; ct < 4; ++ct) {
        float pe = __expf(p[ct][r] - mn);
        p[ct][r] = pe;
        ps += pe;
      }
      ps += __shfl_xor(ps, 1, 64);
      ps += __shfl_xor(ps, 2, 64);
      ps += __shfl_xor(ps, 4, 64);
      ps += __shfl_xor(ps, 8, 64);
      lrow[r] = lrow[r] * alpha + ps;
      O[0][r] *= alpha; O[1][r] *= alpha; O[2][r] *= alpha; O[3][r] *= alpha;
    }

#pragma unroll
    for (int ct = 0; ct < 4; ++ct)
#pragma unroll
      for (int r = 0; r < 4; ++r)
        Pw[(quad * 4 + r) * 72 + ct * 16 + n] = f2bf(p[ct][r]);

#pragma unroll
    for (int ks = 0; ks < 2; ++ks) {
      bf16x8 pa = *(const bf16x8*)&Pw[n * 72 + (ks * 4 + quad) * 8];
      const int gv = (ks * 4 + quad) ^ (n & 7);
#pragma unroll
      for (int ct = 0; ct < 4; ++ct) {
        bf16x8 vb = *(const bf16x8*)&V2[cur][((ct * 16 + n) * 8 + gv) * 8];
        O[ct] = __builtin_amdgcn_mfma_f32_16x16x32_bf16(pa, vb, O[ct], 0, 0, 0);
      }
    }
  }

#pragma unroll
  for (int r = 0; r < 4; ++r) {
    float inv = 1.0f / lrow[r];
    int row = q0 + wave * 16 + quad * 4 + r;
    unsigned short* dst = y + ((size_t)b * T_ + row) * C_ + h * HD_;
#pragma unroll
    for (int ct = 0; ct < 4; ++ct)
      dst[ct * 16 + n] = f2bf(O[ct][r] * inv);
  }
#undef STAGE_KV
}

// ---------------------------------------------------------------------------
// MoE stats + aux loss: single block, 1024 threads = 16 waves; wave w = batch w.
// ---------------------------------------------------------------------------
__launch_bounds__(1024)
__global__ void moe_stats_kernel(const float* __restrict__ gates,
                                 float* __restrict__ out_aux) {
  int wave = threadIdx.x >> 6, lane = threadIdx.x & 63;
  float c0 = 0.f, sp0 = 0.f, sp1 = 0.f;
#pragma unroll
  for (int j = 0; j < 16; ++j) {
    int t = wave * T_ + lane + 64 * j;
    float p0 = gates[2 * t], p1 = gates[2 * t + 1];
    c0  += (p1 > p0) ? 0.f : 1.f;   // argmax==0 count (ties -> expert 0)
    sp0 += p0;
    sp1 += p1;
  }
#pragma unroll
  for (int off = 32; off > 0; off >>= 1) {
    c0  += __shfl_down(c0, off, 64);
    sp0 += __shfl_down(sp0, off, 64);
    sp1 += __shfl_down(sp1, off, 64);
  }
  __shared__ float red[16][3];
  if (lane == 0) { red[wave][0] = c0; red[wave][1] = sp0; red[wave][2] = sp1; }
  __syncthreads();
  if (threadIdx.x == 0) {
    float s = 0.f;
    for (int b = 0; b < B_; ++b) {
      float cc0 = red[b][0];
      float d0 = cc0 * (1.f / T_), d1 = (T_ - cc0) * (1.f / T_);
      float px0 = red[b][1] * (1.f / T_), px1 = red[b][2] * (1.f / T_);
      s += d0 * px0 + d1 * px1;
    }
    out_aux[0] = s * (4.f / 32.f);   // * E*E / (B*E)
  }
}

// ---------------------------------------------------------------------------
extern "C" void kernel_launch(void* const* d_in, const int* in_sizes, int n_in,
                              void* d_out, int out_size, void* d_ws, size_t ws_size,
                              hipStream_t stream) {
  const float* x     = (const float*)d_in[0];
  const float* ln1_w = (const float*)d_in[1];
  const float* ln1_b = (const float*)d_in[2];
  const float* wqkv  = (const float*)d_in[3];
  const float* bqkv  = (const float*)d_in[4];
  const float* wproj = (const float*)d_in[5];
  const float* bproj = (const float*)d_in[6];
  const float* ln2_w = (const float*)d_in[7];
  const float* ln2_b = (const float*)d_in[8];
  const float* wg    = (const float*)d_in[9];
  const float* w1    = (const float*)d_in[10];
  const float* w2    = (const float*)d_in[11];
  const float* w3    = (const float*)d_in[12];
  float* out = (float*)d_out;

  // workspace layout (ushort units)
  unsigned short* wsu   = (unsigned short*)d_ws;
  unsigned short* wqkvT = wsu;                                   // 2304*768
  unsigned short* wprojT= wqkvT + (size_t)C3_ * C_;              // 768*768
  unsigned short* w1T   = wprojT + (size_t)C_ * C_;              // 2*3072*768
  unsigned short* w2T   = w1T + (size_t)2 * FF_ * C_;            // 2*3072*3072
  unsigned short* w3T   = w2T + (size_t)2 * FF_ * FF_;           // 2*768*3072
  unsigned short* hb    = w3T + (size_t)2 * C_ * FF_;            // BT*C
  unsigned short* region= hb + (size_t)BT_ * C_;                 // BT*4C (attn) / big-MoE
  // attn phase: qkb (BT*2C) | vT (BT*C) | yb (BT*C)  == BT*4C exactly
  unsigned short* qkb   = region;
  unsigned short* vTb   = region + (size_t)BT_ * QK2_;
  unsigned short* yb    = region + (size_t)BT_ * 3 * C_;

  // Big-workspace MoE layout: hh1[2 experts] + hh2[2 experts], each MCH*FF.
  const size_t regionElems = (size_t)BT_ * 4 * C_;               // 50.3M us
  const size_t bigElems    = (size_t)4 * MCH_ * FF_;             // 100.7M us
  const size_t baseElems   = (size_t)(region - wsu);
  const bool   big = ws_size >= (baseElems + bigElems + 65536) * sizeof(unsigned short);

  float* gates = (float*)(region + (big ? bigElems : regionElems));  // BT*2 f32

  // ---- weight transpose+convert: ONE batched launch ----
  {
    CtJobs J;
    int idx = 0, acc = 0;
    auto add = [&](const float* in, unsigned short* outp, int K, int N) {
      J.in[idx] = in; J.out[idx] = outp; J.K[idx] = K; J.N[idx] = N;
      J.tX[idx] = N / 32; J.t0[idx] = acc;
      acc += (N / 32) * (K / 32);
      ++idx;
    };
    add(wqkv, wqkvT, C_, C3_);
    add(wproj, wprojT, C_, C_);
    for (int e = 0; e < 2; ++e) {
      add(w1 + (size_t)e * C_ * FF_, w1T + (size_t)e * FF_ * C_, C_, FF_);
      add(w2 + (size_t)e * FF_ * FF_, w2T + (size_t)e * FF_ * FF_, FF_, FF_);
      add(w3 + (size_t)e * FF_ * C_, w3T + (size_t)e * C_ * FF_, FF_, C_);
    }
    J.t0[8] = acc;
    convT_batch<<<acc, 256, 0, stream>>>(J);
  }

  // ---- attention path ----
  ln_kernel<false><<<BT_, 256, 0, stream>>>(x, ln1_w, ln1_b, hb, nullptr, nullptr);
  gemm_bf16<0, true, false, false, true, true><<<dim3(C3_ / 128, BT_ / 128), 256, 0, stream>>>(
      hb, wqkvT, bqkv, nullptr, nullptr, 0, qkb, vTb, BT_, C3_, C_, 0, 0);
  attn_kernel<<<dim3(T_ / 128, B_ * H_), 512, 0, stream>>>(qkb, vTb, yb);
  gemm_bf16<0, true, true, false, false><<<dim3(C_ / 128, BT_ / 128), 256, 0, stream>>>(
      yb, wprojT, bproj, x, nullptr, 0, out, nullptr, BT_, C_, C_, 0, 0);

  // ---- MoE path (dense: E=2 top-2 -> every token hits both experts) ----
  // ln2 + gating fused (gates from f32 values; saves a launch + h2 re-read)
  ln_kernel<true><<<BT_, 256, 0, stream>>>(out, ln2_w, ln2_b, hb, wg, gates);
  moe_stats_kernel<<<1, 1024, 0, stream>>>(gates, out + (size_t)BT_ * C_);

  if (big) {
    // z-batched experts: w1/w2 on 256^2 4-phase (grid 768 = 3.0 rounds @
    // 1 blk/CU), w3 on 128^2 (grid 768 = 1.0 round @ 3 blk/CU) atomic COMBINE.
    unsigned short* hh1b = region;                               // [e][MCH*FF]
    unsigned short* hh2b = region + (size_t)2 * MCH_ * FF_;      // [e][MCH*FF]
    for (int c = 0; c < BT_ / MCH_; ++c) {
      const unsigned short* a = hb + (size_t)c * MCH_ * C_;
      gemm256<1, false><<<dim3(FF_ / 256, MCH_ / 256, 2), 512, 0, stream>>>(
          a, w1T, nullptr, hh1b, MCH_, FF_, C_,
          0, (size_t)FF_ * C_, (size_t)MCH_ * FF_);
      gemm256<1, false><<<dim3(FF_ / 256, MCH_ / 256, 2), 512, 0, stream>>>(
          hh1b, w2T, nullptr, hh2b, MCH_, FF_, FF_,
          (size_t)MCH_ * FF_, (size_t)FF_ * FF_, (size_t)MCH_ * FF_);
      gemm_bf16<0, false, false, true, false, false, true>
          <<<dim3(C_ / 128, MCH_ / 128, 2), 256, 0, stream>>>(
          hh2b, w3T, nullptr, nullptr,
          gates + (size_t)2 * c * MCH_, 0, out + (size_t)c * MCH_ * C_, nullptr,
          MCH_, C_, FF_, (size_t)MCH_ * FF_, (size_t)C_ * FF_);
    }
  } else {
    // fallback: proven sequential path
    unsigned short* hh1 = region;
    unsigned short* hh2 = region + (size_t)MCH_ * FF_;
    for (int e = 0; e < 2; ++e) {
      for (int c = 0; c < BT_ / MCH_; ++c) {
        const unsigned short* a = hb + (size_t)c * MCH_ * C_;
        gemm_bf16<1, false, false, false, true><<<dim3(FF_ / 128, MCH_ / 128), 256, 0, stream>>>(
            a, w1T + (size_t)e * FF_ * C_, nullptr, nullptr, nullptr, 0, hh1, nullptr,
            MCH_, FF_, C_, 0, 0);
        gemm_bf16<1, false, false, false, true><<<dim3(FF_ / 128, MCH_ / 128), 256, 0, stream>>>(
            hh1, w2T + (size_t)e * FF_ * FF_, nullptr, nullptr, nullptr, 0, hh2, nullptr,
            MCH_, FF_, FF_, 0, 0);
        gemm_bf16<0, false, false, true, false><<<dim3(C_ / 128, MCH_ / 128), 256, 0, stream>>>(
            hh2, w3T + (size_t)e * C_ * FF_, nullptr, nullptr,
            gates + (size_t)2 * c * MCH_, e, out + (size_t)c * MCH_ * C_, nullptr,
            MCH_, C_, FF_, 0, 0);
      }
    }
  }
}

// Round 10
// 1488.555 us; speedup vs baseline: 1.0698x; 1.0698x over previous
//
#include <hip/hip_runtime.h>
#include <cstdint>
#include <cstddef>

// Problem constants (fixed by setup_inputs)
constexpr int B_  = 16;
constexpr int T_  = 1024;
constexpr int C_  = 768;
constexpr int H_  = 12;
constexpr int HD_ = 64;
constexpr int BT_ = B_ * T_;      // 16384
constexpr int C3_ = 3 * C_;       // 2304
constexpr int QK2_ = 2 * C_;      // 1536 (packed q|k row stride)
constexpr int FF_ = 4 * C_;       // 3072
constexpr int MCH_ = 8192;        // MoE row chunk (fallback tiers)

typedef __bf16 bf16x8 __attribute__((ext_vector_type(8)));
typedef float  floatx4 __attribute__((ext_vector_type(4)));
typedef unsigned short u16x8 __attribute__((ext_vector_type(8)));

__device__ inline float bf2f(unsigned short u) {
  union { unsigned int i; float f; } x; x.i = ((unsigned int)u) << 16; return x.f;
}
__device__ inline unsigned short f2bf(float f) {
  union { float f; unsigned int i; } x; x.f = f;
  unsigned int u = x.i;
  u += 0x7fffu + ((u >> 16) & 1u);   // round-to-nearest-even
  return (unsigned short)(u >> 16);
}

// async global->LDS, 16B per lane, LDS dest = wave-uniform base + lane*16
#define GLOAD_LDS16(gp, lp)                                              \
  __builtin_amdgcn_global_load_lds(                                      \
      (__attribute__((address_space(1))) void*)(gp),                     \
      (__attribute__((address_space(3))) void*)(lp), 16, 0, 0)

// ---------------------------------------------------------------------------
// LayerNorm: one block (256 threads) per row of 768. f32 in, bf16 out.
// GATE: fused MoE gating (h2 @ wg -> softmax -> gates).
// ---------------------------------------------------------------------------
template <bool GATE>
__launch_bounds__(256)
__global__ void ln_kernel(const float* __restrict__ x, const float* __restrict__ w,
                          const float* __restrict__ b, unsigned short* __restrict__ out,
                          const float* __restrict__ wg, float* __restrict__ gates) {
  int row = blockIdx.x;
  int tid = threadIdx.x;
  const float* xr = x + (size_t)row * C_;
  float v0 = xr[tid], v1 = xr[tid + 256], v2 = xr[tid + 512];
  float s  = v0 + v1 + v2;
  float ss = v0 * v0 + v1 * v1 + v2 * v2;
#pragma unroll
  for (int off = 32; off > 0; off >>= 1) {
    s  += __shfl_down(s, off, 64);
    ss += __shfl_down(ss, off, 64);
  }
  __shared__ float red[8];
  int wid = tid >> 6;
  if ((tid & 63) == 0) { red[wid] = s; red[4 + wid] = ss; }
  __syncthreads();
  float st  = red[0] + red[1] + red[2] + red[3];
  float sst = red[4] + red[5] + red[6] + red[7];
  float mean = st * (1.0f / C_);
  float var  = sst * (1.0f / C_) - mean * mean;
  float rstd = rsqrtf(var + 1e-5f);
  float h0 = (v0 - mean) * rstd * w[tid]       + b[tid];
  float h1 = (v1 - mean) * rstd * w[tid + 256] + b[tid + 256];
  float h2 = (v2 - mean) * rstd * w[tid + 512] + b[tid + 512];
  unsigned short* orow = out + (size_t)row * C_;
  orow[tid]       = f2bf(h0);
  orow[tid + 256] = f2bf(h1);
  orow[tid + 512] = f2bf(h2);

  if (GATE) {
    float a0 = h0 * wg[2 * tid]     + h1 * wg[2 * (tid + 256)]     + h2 * wg[2 * (tid + 512)];
    float a1 = h0 * wg[2 * tid + 1] + h1 * wg[2 * (tid + 256) + 1] + h2 * wg[2 * (tid + 512) + 1];
#pragma unroll
    for (int off = 32; off > 0; off >>= 1) {
      a0 += __shfl_down(a0, off, 64);
      a1 += __shfl_down(a1, off, 64);
    }
    __shared__ float redg[8];
    if ((tid & 63) == 0) { redg[wid] = a0; redg[4 + wid] = a1; }
    __syncthreads();
    if (tid == 0) {
      float A0 = redg[0] + redg[1] + redg[2] + redg[3];
      float A1 = redg[4] + redg[5] + redg[6] + redg[7];
      float m  = fmaxf(A0, A1);
      float e0 = __expf(A0 - m), e1 = __expf(A1 - m);
      float invs = 1.0f / (e0 + e1);
      const float gnorm = 1.0f / (1.0f + 1e-9f);
      gates[2 * row]     = e0 * invs * gnorm;
      gates[2 * row + 1] = e1 * invs * gnorm;
    }
  }
}

// ---------------------------------------------------------------------------
// Batched transpose+convert: all weight matrices in ONE launch.
// ---------------------------------------------------------------------------
struct CtJobs {
  const float* in[8];
  unsigned short* out[8];
  int K[8], N[8], tX[8];
  int t0[9];
};

__launch_bounds__(256)
__global__ void convT_batch(CtJobs J) {
  __shared__ float t[32][33];
  int bid = blockIdx.x;
  int ji = 0;
#pragma unroll
  for (int i = 0; i < 7; ++i) ji += (bid >= J.t0[i + 1]) ? 1 : 0;
  const float* in = J.in[ji];
  unsigned short* out = J.out[ji];
  const int K = J.K[ji], N = J.N[ji];
  const int lt = bid - J.t0[ji];
  const int bx = lt % J.tX[ji], by = lt / J.tX[ji];
  const int n0 = bx * 32, k0 = by * 32;
  const int tx = threadIdx.x & 31, ty = threadIdx.x >> 5;  // 8 rows per pass
#pragma unroll
  for (int r = 0; r < 32; r += 8)
    t[r + ty][tx] = in[(size_t)(k0 + r + ty) * N + n0 + tx];
  __syncthreads();
#pragma unroll
  for (int r = 0; r < 32; r += 8)
    out[(size_t)(n0 + r + ty) * K + k0 + tx] = f2bf(t[tx][r + ty]);
}

// ---------------------------------------------------------------------------
// bf16 MFMA GEMM: C = post(A @ Bt^T). 128x128 tile / 256 threads, T1 swizzle.
// VSPLIT (qkv only): cols [0,2C) -> packed qk; cols [2C,3C) -> vT (V^T).
// ZB: blockIdx.z selects expert; COMBINE then uses atomicAdd.
// ---------------------------------------------------------------------------
template <int ACT, bool BIAS, bool RES, bool COMBINE, bool OUTBF16,
          bool VSPLIT = false, bool ZB = false>
__launch_bounds__(256)
__global__ void gemm_bf16(const unsigned short* __restrict__ A,
                          const unsigned short* __restrict__ Bt,
                          const float* __restrict__ bias,
                          const float* __restrict__ Rres,
                          const float* __restrict__ gates2, int eidx,
                          void* __restrict__ Cout,
                          unsigned short* __restrict__ vtout,
                          int M, int N, int K,
                          size_t zsA, size_t zsB) {
  __shared__ __attribute__((aligned(16))) unsigned short Als[8192];
  __shared__ __attribute__((aligned(16))) unsigned short Bls[8192];
  const int tid  = threadIdx.x;
  const int wave = tid >> 6, lane = tid & 63;
  const int wr = wave >> 1, wc = wave & 1;

  if (ZB) {
    A  += (size_t)blockIdx.z * zsA;
    Bt += (size_t)blockIdx.z * zsB;
    eidx = (int)blockIdx.z;
  }

  // XCD-aware bijective swizzle (all grids here have nwg % 8 == 0)
  int bx = blockIdx.x, by = blockIdx.y;
  {
    const int nbx = gridDim.x;
    const int nwg = nbx * gridDim.y;
    if ((nwg & 7) == 0) {
      const int bid = by * nbx + bx;
      const int swz = (bid & 7) * (nwg >> 3) + (bid >> 3);
      by = swz / nbx; bx = swz - by * nbx;
    }
  }
  const int m0 = by * 128, n0 = bx * 128;

  const int srow = wave * 32 + (lane >> 3);
  const int skg  = (lane & 7) ^ ((lane >> 3) & 7);   // swizzled k-granule
  const unsigned short* Ap = A  + (size_t)(m0 + srow) * K + skg * 8;
  const unsigned short* Bp = Bt + (size_t)(n0 + srow) * K + skg * 8;
  unsigned short* AlsW = Als + wave * 2048;
  unsigned short* BlsW = Bls + wave * 2048;

  floatx4 acc[4][4];
#pragma unroll
  for (int i = 0; i < 4; ++i)
#pragma unroll
    for (int j = 0; j < 4; ++j) acc[i][j] = floatx4{0.f, 0.f, 0.f, 0.f};

  const int q  = lane >> 4;
  const int ml = lane & 15;
  const int rsw = ml & 7;

  for (int k0 = 0; k0 < K; k0 += 64) {
    __syncthreads();
#pragma unroll
    for (int i = 0; i < 4; ++i) {
      GLOAD_LDS16(Ap + (size_t)(i * 8) * K + k0, AlsW + i * 512);
      GLOAD_LDS16(Bp + (size_t)(i * 8) * K + k0, BlsW + i * 512);
    }
    __syncthreads();
#pragma unroll
    for (int ks = 0; ks < 2; ++ks) {
      const int p = (ks * 4 + q) ^ rsw;
      bf16x8 af[4], bfg[4];
#pragma unroll
      for (int i = 0; i < 4; ++i) {
        int ar = wr * 64 + i * 16 + ml;
        af[i]  = *(const bf16x8*)&Als[(ar * 8 + p) * 8];
        int br = wc * 64 + i * 16 + ml;
        bfg[i] = *(const bf16x8*)&Bls[(br * 8 + p) * 8];
      }
#pragma unroll
      for (int i = 0; i < 4; ++i)
#pragma unroll
        for (int j = 0; j < 4; ++j)
          acc[i][j] = __builtin_amdgcn_mfma_f32_16x16x32_bf16(af[i], bfg[j], acc[i][j], 0, 0, 0);
    }
  }

  const int rbase = q * 4;
#pragma unroll
  for (int i = 0; i < 4; ++i) {
    int row = m0 + wr * 64 + i * 16 + rbase;
#pragma unroll
    for (int j = 0; j < 4; ++j) {
      int col = n0 + wc * 64 + j * 16 + ml;
      float bcol = BIAS ? bias[col] : 0.f;
#pragma unroll
      for (int r = 0; r < 4; ++r) {
        float v = acc[i][j][r];
        if (BIAS) v += bcol;
        if (ACT == 1) v = (v >= 0.f) ? v : 0.01f * v;
        if (RES) v += Rres[(size_t)(row + r) * N + col];
        if (COMBINE) {
          float g = gates2[2 * (row + r) + eidx];
          float* op = (float*)Cout + (size_t)(row + r) * N + col;
          if (ZB) atomicAdd(op, g * v);
          else    *op += g * v;
        } else if (VSPLIT) {
          if (col < QK2_) {
            ((unsigned short*)Cout)[(size_t)(row + r) * QK2_ + col] = f2bf(v);
          } else {
            vtout[(size_t)(col - QK2_) * BT_ + row + r] = f2bf(v);
          }
        } else if (OUTBF16) {
          ((unsigned short*)Cout)[(size_t)(row + r) * N + col] = f2bf(v);
        } else {
          ((float*)Cout)[(size_t)(row + r) * N + col] = v;
        }
      }
    }
  }
}

// ---------------------------------------------------------------------------
// 256x256-tile bf16 GEMM -- round-5 proven 4-phase schedule + T1 swizzle
// (round-9: FETCH 473->358 MB confirmed; time unchanged -> structure-bound
// at 45% MfmaUtil, 1 block/CU, VGPR-capped at 2 waves/SIMD).
// blockIdx.z = expert (z-strides on A/B/C).
// ---------------------------------------------------------------------------
#define GB256_BAR()   asm volatile("s_barrier" ::: "memory")
#define GB256_LGKM0() asm volatile("s_waitcnt lgkmcnt(0)" ::: "memory")

template <int ACT, bool BIAS>
__launch_bounds__(512, 2)
__global__ void gemm256(const unsigned short* __restrict__ A,
                        const unsigned short* __restrict__ Bt,
                        const float* __restrict__ bias,
                        unsigned short* __restrict__ Cout,
                        int M, int N, int K,
                        size_t zsA, size_t zsB, size_t zsC) {
  // [buf(2)][mat(2)][ks(2)][256*32] ushorts = 128 KB
  __shared__ __attribute__((aligned(16))) unsigned short L[65536];
  const int tid = threadIdx.x;
  const int w = tid >> 6, l = tid & 63;
  const int wr = w >> 2, wc = w & 3;
  const int ml = l & 15, q = l >> 4;

  A    += (size_t)blockIdx.z * zsA;
  Bt   += (size_t)blockIdx.z * zsB;
  Cout += (size_t)blockIdx.z * zsC;

  // T1 XCD-aware bijective swizzle on (x,y) within each z-slice
  int bx = blockIdx.x, by = blockIdx.y;
  {
    const int nbx = gridDim.x;
    const int nwg = nbx * gridDim.y;
    if ((nwg & 7) == 0) {
      const int bid = by * nbx + bx;
      const int swz = (bid & 7) * (nwg >> 3) + (bid >> 3);
      by = swz / nbx; bx = swz - by * nbx;
    }
  }
  const int m0 = by * 256, n0 = bx * 256;

  const int srow = l >> 2;                                // row within 16-chunk
  const int sg   = ((l & 3) ^ ((l >> 3) & 3)) * 8;        // swizzled src col (elems)
  const unsigned short* Ast = A  + (size_t)(m0 + srow) * K + sg;
  const unsigned short* Bst = Bt + (size_t)(n0 + srow) * K + sg;
  const int ldsw = w * 1024;                              // wave rows w*32..

#define STG(cb, mat, ks, srcp, kk)                                           \
  do {                                                                       \
    const unsigned short* _s = (srcp) + (size_t)(w * 32) * K + (kk) + (ks) * 32; \
    unsigned short* _d = L + (cb) * 32768 + (mat) * 16384 + (ks) * 8192 + ldsw;  \
    GLOAD_LDS16(_s, _d);                                                     \
    GLOAD_LDS16(_s + (size_t)16 * K, _d + 512);                              \
  } while (0)

  const int dphys = (q ^ ((ml >> 1) & 3)) * 8;
  const int aoff = (wr * 128 + ml) * 32 + dphys;          // + m*512
  const int boff = (wc * 64 + ml) * 32 + dphys;           // + n*512

  floatx4 acc[8][4];
#pragma unroll
  for (int m = 0; m < 8; ++m)
#pragma unroll
    for (int n = 0; n < 4; ++n) acc[m][n] = floatx4{0.f, 0.f, 0.f, 0.f};

  const int NT = K >> 6;

  STG(0, 0, 0, Ast, 0);  STG(0, 1, 0, Bst, 0);
  STG(0, 0, 1, Ast, 0);  STG(0, 1, 1, Bst, 0);
  STG(1, 0, 0, Ast, 64); STG(1, 1, 0, Bst, 64);
  asm volatile("s_waitcnt vmcnt(0)" ::: "memory");
  GB256_BAR();

  for (int j = 0; j < NT; ++j) {
    const int c = j & 1, nx = c ^ 1;
    const int kk1 = (j + 1) << 6, kk2 = (j + 2) << 6;
    const bool st1 = (j + 1 < NT), st2 = (j + 2 < NT);
    bf16x8 bA[4], bB[4];

#define LOAD_A(KS, MH)                                                       \
  _Pragma("unroll")                                                          \
  for (int mq = 0; mq < 4; ++mq)                                             \
    bA[mq] = *(const bf16x8*)&L[c * 32768 + (KS) * 8192 + aoff + ((MH) * 4 + mq) * 512];
#define LOAD_B(KS)                                                           \
  _Pragma("unroll")                                                          \
  for (int n = 0; n < 4; ++n)                                                \
    bB[n] = *(const bf16x8*)&L[c * 32768 + 16384 + (KS) * 8192 + boff + n * 512];
#define MFMA16(MH)                                                           \
  __builtin_amdgcn_s_setprio(1);                                             \
  _Pragma("unroll")                                                          \
  for (int mq = 0; mq < 4; ++mq)                                             \
    _Pragma("unroll")                                                        \
    for (int n = 0; n < 4; ++n)                                              \
      acc[(MH) * 4 + mq][n] = __builtin_amdgcn_mfma_f32_16x16x32_bf16(       \
          bA[mq], bB[n], acc[(MH) * 4 + mq][n], 0, 0, 0);                    \
  __builtin_amdgcn_s_setprio(0);

    // ---- p1: ks0, mh0 ----
    LOAD_B(0); LOAD_A(0, 0);
    if (st1) STG(nx, 0, 1, Ast, kk1);
    GB256_BAR(); GB256_LGKM0();
    MFMA16(0);
    GB256_BAR();

    // ---- p2: ks0, mh1 ----
    LOAD_A(0, 1);
    if (st1) STG(nx, 1, 1, Bst, kk1);
    GB256_BAR(); GB256_LGKM0();
    MFMA16(1);
    GB256_BAR();

    // ---- p3: ks1, mh0 ----
    LOAD_B(1); LOAD_A(1, 0);
    if (st2) STG(c, 0, 0, Ast, kk2);
    GB256_BAR(); GB256_LGKM0();
    MFMA16(0);
    GB256_BAR();

    // ---- p4: ks1, mh1 ----
    LOAD_A(1, 1);
    if (st2) STG(c, 1, 0, Bst, kk2);
    GB256_BAR(); GB256_LGKM0();
    MFMA16(1);
    if (st2)      asm volatile("s_waitcnt vmcnt(4)" ::: "memory");
    else if (st1) asm volatile("s_waitcnt vmcnt(0)" ::: "memory");
    GB256_BAR();
#undef LOAD_A
#undef LOAD_B
#undef MFMA16
  }

#pragma unroll
  for (int m = 0; m < 8; ++m) {
    const int row = m0 + wr * 128 + m * 16 + q * 4;
#pragma unroll
    for (int n = 0; n < 4; ++n) {
      const int col = n0 + wc * 64 + n * 16 + ml;
      const float bcol = BIAS ? bias[col] : 0.f;
#pragma unroll
      for (int r = 0; r < 4; ++r) {
        float v = acc[m][n][r];
        if (BIAS) v += bcol;
        if (ACT == 1) v = (v >= 0.f) ? v : 0.01f * v;
        Cout[(size_t)(row + r) * N + col] = f2bf(v);
      }
    }
  }
#undef STG
}

// ---------------------------------------------------------------------------
// MFMA flash attention, QBLK=128 (8 waves / 512 threads), double-buffered
// K/V staged ONCE per 128 Q-rows; LDS 66.5 KB -> 2 blocks/CU. Per-wave
// dead-tile skip (wave-uniform). T5 setprio around MFMA clusters (m191:
// attn +4-7%, A/B-verified). qk: [B*T,2C] bf16. vT: [C,B*T]. y: bf16.
// ---------------------------------------------------------------------------
__launch_bounds__(512)
__global__ void attn_kernel(const unsigned short* __restrict__ qk,
                            const unsigned short* __restrict__ vT,
                            unsigned short* __restrict__ y) {
  __shared__ __attribute__((aligned(16))) unsigned short Qls[128 * 64];
  __shared__ __attribute__((aligned(16))) unsigned short K2[2][64 * 64];
  __shared__ __attribute__((aligned(16))) unsigned short V2[2][64 * 64];
  __shared__ __attribute__((aligned(16))) unsigned short Pls[8 * 16 * 72];

  const int tid  = threadIdx.x;
  const int wave = tid >> 6, lane = tid & 63;
  const int quad = lane >> 4, n = lane & 15;
  const int q0 = blockIdx.x * 128;
  const int bh = blockIdx.y;
  const int b = bh / H_, h = bh % H_;
  const size_t qbase = (size_t)b * T_ * QK2_ + (size_t)h * HD_;
  const size_t vbase = (size_t)h * HD_ * BT_ + (size_t)b * T_;

  const int r8 = lane >> 3;            // 0..7
  const int g  = (lane & 7) ^ r8;      // swizzled granule (16B units), row&7 XOR

  // Q stage (once): wave stages its own 16 rows (2 x 8-row GLOADs)
#pragma unroll
  for (int i = 0; i < 2; ++i) {
    int row = wave * 16 + i * 8 + r8;
    GLOAD_LDS16(qk + qbase + (size_t)(q0 + row) * QK2_ + g * 8,
                Qls + wave * 1024 + i * 512);
  }

  // K/V stage: 8 waves x 8 rows each (1 GLOAD K + 1 GLOAD V per wave)
#define STAGE_KV(bf, k0)                                                      \
  do {                                                                        \
    int row = wave * 8 + r8;                                                  \
    GLOAD_LDS16(qk + qbase + (size_t)((k0) + row) * QK2_ + C_ + g * 8,        \
                K2[bf] + wave * 512);                                         \
    GLOAD_LDS16(vT + vbase + (size_t)row * BT_ + (k0) + g * 8,                \
                V2[bf] + wave * 512);                                         \
  } while (0)

  STAGE_KV(0, 0);

  floatx4 O[4];
#pragma unroll
  for (int ct = 0; ct < 4; ++ct) O[ct] = floatx4{0.f, 0.f, 0.f, 0.f};
  float mrow[4] = {-1e30f, -1e30f, -1e30f, -1e30f};
  float lrow[4] = {0.f, 0.f, 0.f, 0.f};

  const int nkt = 2 * blockIdx.x + 2;
  const int dt  = 2 * blockIdx.x + (wave >> 2);   // wave's diagonal tile
  unsigned short* Pw = Pls + wave * (16 * 72);

  for (int kt = 0; kt < nkt; ++kt) {
    const int cur = kt & 1;
    __syncthreads();                    // drains vmcnt(0): buf[cur] ready
    if (kt + 1 < nkt) STAGE_KV(cur ^ 1, (kt + 1) << 6);
    if (kt > dt) continue;              // fully-masked tile for this wave

    floatx4 sacc[4];
#pragma unroll
    for (int ct = 0; ct < 4; ++ct) sacc[ct] = floatx4{0.f, 0.f, 0.f, 0.f};
    __builtin_amdgcn_s_setprio(1);
#pragma unroll
    for (int ks = 0; ks < 2; ++ks) {
      const int ga = (ks * 4 + quad) ^ (n & 7);
      bf16x8 aq = *(const bf16x8*)&Qls[((wave * 16 + n) * 8 + ga) * 8];
#pragma unroll
      for (int ct = 0; ct < 4; ++ct) {
        bf16x8 kb = *(const bf16x8*)&K2[cur][((ct * 16 + n) * 8 + ga) * 8];
        sacc[ct] = __builtin_amdgcn_mfma_f32_16x16x32_bf16(aq, kb, sacc[ct], 0, 0, 0);
      }
    }
    __builtin_amdgcn_s_setprio(0);

    float p[4][4];
#pragma unroll
    for (int ct = 0; ct < 4; ++ct)
#pragma unroll
      for (int r = 0; r < 4; ++r) p[ct][r] = sacc[ct][r] * 0.125f;
    if (kt == dt) {                     // diagonal tile: causal mask
      const int kgb = (kt << 6) + n, qgb = q0 + wave * 16 + quad * 4;
#pragma unroll
      for (int ct = 0; ct < 4; ++ct)
#pragma unroll
        for (int r = 0; r < 4; ++r)
          if (kgb + ct * 16 > qgb + r) p[ct][r] = -1e30f;
    }
#pragma unroll
    for (int r = 0; r < 4; ++r) {
      float tm = fmaxf(fmaxf(p[0][r], p[1][r]), fmaxf(p[2][r], p[3][r]));
      tm = fmaxf(tm, __shfl_xor(tm, 1, 64));
      tm = fmaxf(tm, __shfl_xor(tm, 2, 64));
      tm = fmaxf(tm, __shfl_xor(tm, 4, 64));
      tm = fmaxf(tm, __shfl_xor(tm, 8, 64));
      float mn = fmaxf(mrow[r], tm);
      float alpha = __expf(mrow[r] - mn);
      mrow[r] = mn;
      float ps = 0.f;
#pragma unroll
      for (int ct = 0; ct < 4; ++ct) {
        float pe = __expf(p[ct][r] - mn);
        p[ct][r] = pe;
        ps += pe;
      }
      ps += __shfl_xor(ps, 1, 64);
      ps += __shfl_xor(ps, 2, 64);
      ps += __shfl_xor(ps, 4, 64);
      ps += __shfl_xor(ps, 8, 64);
      lrow[r] = lrow[r] * alpha + ps;
      O[0][r] *= alpha; O[1][r] *= alpha; O[2][r] *= alpha; O[3][r] *= alpha;
    }

#pragma unroll
    for (int ct = 0; ct < 4; ++ct)
#pragma unroll
      for (int r = 0; r < 4; ++r)
        Pw[(quad * 4 + r) * 72 + ct * 16 + n] = f2bf(p[ct][r]);

    __builtin_amdgcn_s_setprio(1);
#pragma unroll
    for (int ks = 0; ks < 2; ++ks) {
      bf16x8 pa = *(const bf16x8*)&Pw[n * 72 + (ks * 4 + quad) * 8];
      const int gv = (ks * 4 + quad) ^ (n & 7);
#pragma unroll
      for (int ct = 0; ct < 4; ++ct) {
        bf16x8 vb = *(const bf16x8*)&V2[cur][((ct * 16 + n) * 8 + gv) * 8];
        O[ct] = __builtin_amdgcn_mfma_f32_16x16x32_bf16(pa, vb, O[ct], 0, 0, 0);
      }
    }
    __builtin_amdgcn_s_setprio(0);
  }

#pragma unroll
  for (int r = 0; r < 4; ++r) {
    float inv = 1.0f / lrow[r];
    int row = q0 + wave * 16 + quad * 4 + r;
    unsigned short* dst = y + ((size_t)b * T_ + row) * C_ + h * HD_;
#pragma unroll
    for (int ct = 0; ct < 4; ++ct)
      dst[ct * 16 + n] = f2bf(O[ct][r] * inv);
  }
#undef STAGE_KV
}

// ---------------------------------------------------------------------------
// MoE stats + aux loss: single block, 1024 threads = 16 waves; wave w = batch w.
// ---------------------------------------------------------------------------
__launch_bounds__(1024)
__global__ void moe_stats_kernel(const float* __restrict__ gates,
                                 float* __restrict__ out_aux) {
  int wave = threadIdx.x >> 6, lane = threadIdx.x & 63;
  float c0 = 0.f, sp0 = 0.f, sp1 = 0.f;
#pragma unroll
  for (int j = 0; j < 16; ++j) {
    int t = wave * T_ + lane + 64 * j;
    float p0 = gates[2 * t], p1 = gates[2 * t + 1];
    c0  += (p1 > p0) ? 0.f : 1.f;   // argmax==0 count (ties -> expert 0)
    sp0 += p0;
    sp1 += p1;
  }
#pragma unroll
  for (int off = 32; off > 0; off >>= 1) {
    c0  += __shfl_down(c0, off, 64);
    sp0 += __shfl_down(sp0, off, 64);
    sp1 += __shfl_down(sp1, off, 64);
  }
  __shared__ float red[16][3];
  if (lane == 0) { red[wave][0] = c0; red[wave][1] = sp0; red[wave][2] = sp1; }
  __syncthreads();
  if (threadIdx.x == 0) {
    float s = 0.f;
    for (int b = 0; b < B_; ++b) {
      float cc0 = red[b][0];
      float d0 = cc0 * (1.f / T_), d1 = (T_ - cc0) * (1.f / T_);
      float px0 = red[b][1] * (1.f / T_), px1 = red[b][2] * (1.f / T_);
      s += d0 * px0 + d1 * px1;
    }
    out_aux[0] = s * (4.f / 32.f);   // * E*E / (B*E)
  }
}

// ---------------------------------------------------------------------------
extern "C" void kernel_launch(void* const* d_in, const int* in_sizes, int n_in,
                              void* d_out, int out_size, void* d_ws, size_t ws_size,
                              hipStream_t stream) {
  const float* x     = (const float*)d_in[0];
  const float* ln1_w = (const float*)d_in[1];
  const float* ln1_b = (const float*)d_in[2];
  const float* wqkv  = (const float*)d_in[3];
  const float* bqkv  = (const float*)d_in[4];
  const float* wproj = (const float*)d_in[5];
  const float* bproj = (const float*)d_in[6];
  const float* ln2_w = (const float*)d_in[7];
  const float* ln2_b = (const float*)d_in[8];
  const float* wg    = (const float*)d_in[9];
  const float* w1    = (const float*)d_in[10];
  const float* w2    = (const float*)d_in[11];
  const float* w3    = (const float*)d_in[12];
  float* out = (float*)d_out;

  // workspace layout (ushort units)
  unsigned short* wsu   = (unsigned short*)d_ws;
  unsigned short* wqkvT = wsu;                                   // 2304*768
  unsigned short* wprojT= wqkvT + (size_t)C3_ * C_;              // 768*768
  unsigned short* w1T   = wprojT + (size_t)C_ * C_;              // 2*3072*768
  unsigned short* w2T   = w1T + (size_t)2 * FF_ * C_;            // 2*3072*3072
  unsigned short* w3T   = w2T + (size_t)2 * FF_ * FF_;           // 2*768*3072
  unsigned short* hb    = w3T + (size_t)2 * C_ * FF_;            // BT*C
  unsigned short* region= hb + (size_t)BT_ * C_;                 // union area
  // attn phase: qkb (BT*2C) | vT (BT*C) | yb (BT*C)  == BT*4C exactly
  unsigned short* qkb   = region;
  unsigned short* vTb   = region + (size_t)BT_ * QK2_;
  unsigned short* yb    = region + (size_t)BT_ * 3 * C_;

  // Workspace tiers:
  //   big2: hh1[2e][BT*FF] + hh2[2e][BT*FF]  (full-M, single-launch MoE GEMMs)
  //   big : hh1[2e][MCH*FF] + hh2[2e][MCH*FF] (chunked z-batched)
  //   else: sequential fallback
  const size_t regionElems = (size_t)BT_ * 4 * C_;               // 50.3M us
  const size_t bigElems    = (size_t)4 * MCH_ * FF_;             // 100.7M us
  const size_t big2Elems   = (size_t)4 * BT_ * FF_;              // 201.3M us
  const size_t baseElems   = (size_t)(region - wsu);
  const bool   big2 = ws_size >= (baseElems + big2Elems + 65536) * sizeof(unsigned short);
  const bool   big  = ws_size >= (baseElems + bigElems  + 65536) * sizeof(unsigned short);

  float* gates = (float*)(region + (big2 ? big2Elems : big ? bigElems : regionElems));

  // ---- weight transpose+convert: ONE batched launch ----
  {
    CtJobs J;
    int idx = 0, acc = 0;
    auto add = [&](const float* in, unsigned short* outp, int K, int N) {
      J.in[idx] = in; J.out[idx] = outp; J.K[idx] = K; J.N[idx] = N;
      J.tX[idx] = N / 32; J.t0[idx] = acc;
      acc += (N / 32) * (K / 32);
      ++idx;
    };
    add(wqkv, wqkvT, C_, C3_);
    add(wproj, wprojT, C_, C_);
    for (int e = 0; e < 2; ++e) {
      add(w1 + (size_t)e * C_ * FF_, w1T + (size_t)e * FF_ * C_, C_, FF_);
      add(w2 + (size_t)e * FF_ * FF_, w2T + (size_t)e * FF_ * FF_, FF_, FF_);
      add(w3 + (size_t)e * FF_ * C_, w3T + (size_t)e * C_ * FF_, FF_, C_);
    }
    J.t0[8] = acc;
    convT_batch<<<acc, 256, 0, stream>>>(J);
  }

  // ---- attention path ----
  ln_kernel<false><<<BT_, 256, 0, stream>>>(x, ln1_w, ln1_b, hb, nullptr, nullptr);
  gemm_bf16<0, true, false, false, true, true><<<dim3(C3_ / 128, BT_ / 128), 256, 0, stream>>>(
      hb, wqkvT, bqkv, nullptr, nullptr, 0, qkb, vTb, BT_, C3_, C_, 0, 0);
  attn_kernel<<<dim3(T_ / 128, B_ * H_), 512, 0, stream>>>(qkb, vTb, yb);
  gemm_bf16<0, true, true, false, false><<<dim3(C_ / 128, BT_ / 128), 256, 0, stream>>>(
      yb, wprojT, bproj, x, nullptr, 0, out, nullptr, BT_, C_, C_, 0, 0);

  // ---- MoE path (dense: E=2 top-2 -> every token hits both experts) ----
  ln_kernel<true><<<BT_, 256, 0, stream>>>(out, ln2_w, ln2_b, hb, wg, gates);
  moe_stats_kernel<<<1, 1024, 0, stream>>>(gates, out + (size_t)BT_ * C_);

  if (big2) {
    // full-M single-launch MoE: w1/w2 on 256^2 (grid 12x64x2 = 1536 = 6.0
    // rounds @ 1 blk/CU), w3 on 128^2 (grid 6x128x2 = 1536 = 2.0 rounds @
    // 3 blk/CU) with atomic COMBINE. One dispatch per GEMM: removes the
    // per-chunk inter-dispatch drains.
    unsigned short* hh1b = region;                               // [e][BT*FF]
    unsigned short* hh2b = region + (size_t)2 * BT_ * FF_;       // [e][BT*FF]
    gemm256<1, false><<<dim3(FF_ / 256, BT_ / 256, 2), 512, 0, stream>>>(
        hb, w1T, nullptr, hh1b, BT_, FF_, C_,
        0, (size_t)FF_ * C_, (size_t)BT_ * FF_);
    gemm256<1, false><<<dim3(FF_ / 256, BT_ / 256, 2), 512, 0, stream>>>(
        hh1b, w2T, nullptr, hh2b, BT_, FF_, FF_,
        (size_t)BT_ * FF_, (size_t)FF_ * FF_, (size_t)BT_ * FF_);
    gemm_bf16<0, false, false, true, false, false, true>
        <<<dim3(C_ / 128, BT_ / 128, 2), 256, 0, stream>>>(
        hh2b, w3T, nullptr, nullptr,
        gates, 0, out, nullptr,
        BT_, C_, FF_, (size_t)BT_ * FF_, (size_t)C_ * FF_);
  } else if (big) {
    // chunked z-batched path (round-9 proven)
    unsigned short* hh1b = region;                               // [e][MCH*FF]
    unsigned short* hh2b = region + (size_t)2 * MCH_ * FF_;      // [e][MCH*FF]
    for (int c = 0; c < BT_ / MCH_; ++c) {
      const unsigned short* a = hb + (size_t)c * MCH_ * C_;
      gemm256<1, false><<<dim3(FF_ / 256, MCH_ / 256, 2), 512, 0, stream>>>(
          a, w1T, nullptr, hh1b, MCH_, FF_, C_,
          0, (size_t)FF_ * C_, (size_t)MCH_ * FF_);
      gemm256<1, false><<<dim3(FF_ / 256, MCH_ / 256, 2), 512, 0, stream>>>(
          hh1b, w2T, nullptr, hh2b, MCH_, FF_, FF_,
          (size_t)MCH_ * FF_, (size_t)FF_ * FF_, (size_t)MCH_ * FF_);
      gemm_bf16<0, false, false, true, false, false, true>
          <<<dim3(C_ / 128, MCH_ / 128, 2), 256, 0, stream>>>(
          hh2b, w3T, nullptr, nullptr,
          gates + (size_t)2 * c * MCH_, 0, out + (size_t)c * MCH_ * C_, nullptr,
          MCH_, C_, FF_, (size_t)MCH_ * FF_, (size_t)C_ * FF_);
    }
  } else {
    // fallback: proven sequential path
    unsigned short* hh1 = region;
    unsigned short* hh2 = region + (size_t)MCH_ * FF_;
    for (int e = 0; e < 2; ++e) {
      for (int c = 0; c < BT_ / MCH_; ++c) {
        const unsigned short* a = hb + (size_t)c * MCH_ * C_;
        gemm_bf16<1, false, false, false, true><<<dim3(FF_ / 128, MCH_ / 128), 256, 0, stream>>>(
            a, w1T + (size_t)e * FF_ * C_, nullptr, nullptr, nullptr, 0, hh1, nullptr,
            MCH_, FF_, C_, 0, 0);
        gemm_bf16<1, false, false, false, true><<<dim3(FF_ / 128, MCH_ / 128), 256, 0, stream>>>(
            hh1, w2T + (size_t)e * FF_ * FF_, nullptr, nullptr, nullptr, 0, hh2, nullptr,
            MCH_, FF_, FF_, 0, 0);
        gemm_bf16<0, false, false, true, false><<<dim3(C_ / 128, MCH_ / 128), 256, 0, stream>>>(
            hh2, w3T + (size_t)e * C_ * FF_, nullptr, nullptr,
            gates + (size_t)2 * c * MCH_, e, out + (size_t)c * MCH_ * C_, nullptr,
            MCH_, C_, FF_, 0, 0);
      }
    }
  }
}